// Round 1
// baseline (1099.958 us; speedup 1.0000x reference)
//
#include <hip/hip_runtime.h>

#define NN 50000
#define NE 800000
#define NG 1000
#define DIN 64
#define HIDC 64
#define GOUTC 256
#define FPC 2048
#define H1C 1024
#define H2C 512
#define MOUTC 256
#define D1C 512
#define EPSV 1e-5f
#define SLOPEV 0.2f

// ---- GAT: xl = x @ Wg^T ; a_src = xl.att_src ; a_dst = xl.att_dst ----
__global__ void k_xl(const float* __restrict__ x, const float* __restrict__ Wg,
                     const float* __restrict__ att_src, const float* __restrict__ att_dst,
                     float* __restrict__ xl, float* __restrict__ a_src, float* __restrict__ a_dst) {
    __shared__ float Wgs[64][65];
    __shared__ float xs[4][64];
    int t = threadIdx.x;
    int lane = t & 63;        // h channel
    int w = t >> 6;           // node-in-block (one wave per node)
    for (int i = t; i < 64 * 64; i += 256) Wgs[i >> 6][i & 63] = Wg[i];
    int node = blockIdx.x * 4 + w;
    xs[w][lane] = x[node * 64 + lane];
    __syncthreads();
    float acc = 0.f;
#pragma unroll
    for (int d = 0; d < 64; ++d) acc += xs[w][d] * Wgs[lane][d];
    xl[node * 64 + lane] = acc;
    float vs = acc * att_src[lane];
    float vd = acc * att_dst[lane];
#pragma unroll
    for (int off = 32; off > 0; off >>= 1) {
        vs += __shfl_xor(vs, off);
        vd += __shfl_xor(vd, off);
    }
    if (lane == 0) { a_src[node] = vs; a_dst[node] = vd; }
}

// ---- self-loop init of denom/aggr (softmax without max-shift; |e| <~ 1.5) ----
__global__ void k_self_init(const float* __restrict__ xl, const float* __restrict__ a_src,
                            const float* __restrict__ a_dst,
                            float* __restrict__ denom, float* __restrict__ aggr) {
    int t = threadIdx.x, lane = t & 63, w = t >> 6;
    int node = blockIdx.x * 4 + w;
    float e = a_src[node] + a_dst[node];
    e = e > 0.f ? e : SLOPEV * e;
    float ex = expf(e);
    if (lane == 0) denom[node] = ex;
    aggr[node * 64 + lane] = ex * xl[node * 64 + lane];
}

// ---- edge pass: atomic accumulate exp(e) and exp(e)*xl[src] into dst ----
__global__ void k_edges(const int* __restrict__ ei, const float* __restrict__ xl,
                        const float* __restrict__ a_src, const float* __restrict__ a_dst,
                        float* __restrict__ denom, float* __restrict__ aggr) {
    int t = threadIdx.x, lane = t & 63, w = t >> 6;
    int e = blockIdx.x * 4 + w;
    if (e >= NE) return;
    int s = ei[e];
    int d = ei[NE + e];
    float ev = a_src[s] + a_dst[d];
    ev = ev > 0.f ? ev : SLOPEV * ev;
    float ex = expf(ev);
    if (lane == 0) atomicAdd(&denom[d], ex);
    atomicAdd(&aggr[d * 64 + lane], ex * xl[s * 64 + lane]);
}

// ---- relu(gat_out) + global mean pool (sums + counts) ----
__global__ void k_pool(const float* __restrict__ aggr, const float* __restrict__ denom,
                       const float* __restrict__ gat_bias, const int* __restrict__ batch,
                       float* __restrict__ gsum, int* __restrict__ gcnt) {
    int t = threadIdx.x, lane = t & 63, w = t >> 6;
    int node = blockIdx.x * 4 + w;
    float v = aggr[node * 64 + lane] / denom[node] + gat_bias[lane];
    v = v > 0.f ? v : 0.f;
    int b = batch[node];
    atomicAdd(&gsum[b * 64 + lane], v);
    if (lane == 0) atomicAdd(&gcnt[b], 1);
}

__global__ void k_pooled(const float* __restrict__ gsum, const int* __restrict__ gcnt,
                         float* __restrict__ pooled) {
    int i = blockIdx.x * 256 + threadIdx.x;
    if (i < NG * 64) {
        float c = (float)gcnt[i >> 6];
        pooled[i] = gsum[i] / fmaxf(c, 1.f);
    }
}

// ---- generic fp32 GEMM: C[M,N](ldc) = A[M,K] @ B[N,K]^T + bias, opt relu ----
template <bool RELU>
__global__ void k_gemm(const float* __restrict__ A, const float* __restrict__ B,
                       const float* __restrict__ bias, float* __restrict__ C,
                       int M, int N, int K, int ldc) {
    __shared__ float As[64][17];
    __shared__ float Bs[64][17];
    int tx = threadIdx.x & 15, ty = threadIdx.x >> 4;
    int bm = blockIdx.y * 64, bn = blockIdx.x * 64;
    float acc[4][4] = {};
    for (int k0 = 0; k0 < K; k0 += 16) {
        for (int l = threadIdx.x; l < 1024; l += 256) {
            int r = l >> 4, c = l & 15;
            int gr = bm + r;
            As[r][c] = (gr < M) ? A[gr * K + k0 + c] : 0.f;
            Bs[r][c] = B[(bn + r) * K + k0 + c];  // N is multiple of 64
        }
        __syncthreads();
#pragma unroll
        for (int kk = 0; kk < 16; ++kk) {
            float a[4], b[4];
#pragma unroll
            for (int i = 0; i < 4; ++i) a[i] = As[ty + 16 * i][kk];
#pragma unroll
            for (int j = 0; j < 4; ++j) b[j] = Bs[tx + 16 * j][kk];
#pragma unroll
            for (int i = 0; i < 4; ++i)
#pragma unroll
                for (int j = 0; j < 4; ++j) acc[i][j] += a[i] * b[j];
        }
        __syncthreads();
    }
#pragma unroll
    for (int i = 0; i < 4; ++i) {
        int gr = bm + ty + 16 * i;
        if (gr >= M) continue;
#pragma unroll
        for (int j = 0; j < 4; ++j) {
            int gn = bn + tx + 16 * j;
            float v = acc[i][j] + bias[gn];
            if (RELU) v = fmaxf(v, 0.f);
            C[gr * ldc + gn] = v;
        }
    }
}

// ---- BN column stats (training-mode, biased var) -> scale/shift ----
__global__ void k_bnstats(const float* __restrict__ h, const float* __restrict__ gamma,
                          const float* __restrict__ beta, float* __restrict__ scale,
                          float* __restrict__ shift, int ncols) {
    int col = blockIdx.x * 256 + threadIdx.x;
    if (col >= ncols) return;
    float s = 0.f, sq = 0.f;
    for (int r = 0; r < NG; ++r) {
        float v = h[r * ncols + col];
        s += v;
        sq += v * v;
    }
    float mu = s * (1.f / NG);
    float var = sq * (1.f / NG) - mu * mu;
    float rstd = rsqrtf(var + EPSV);
    float sc = gamma[col] * rstd;
    scale[col] = sc;
    shift[col] = beta[col] - mu * sc;
}

__global__ void k_bnrelu(float* __restrict__ h, const float* __restrict__ scale,
                         const float* __restrict__ shift, int colmask, int total) {
    int i = blockIdx.x * 256 + threadIdx.x;
    if (i < total) {
        int col = i & colmask;
        float v = h[i] * scale[col] + shift[col];
        h[i] = fmaxf(v, 0.f);
    }
}

// ---- final: out[g] = sum_j (z[g,j]*scale[j]+shift[j]) * Wl[j] + bl ----
__global__ void k_final(const float* __restrict__ z, const float* __restrict__ scale,
                        const float* __restrict__ shift, const float* __restrict__ Wl,
                        const float* __restrict__ bl, float* __restrict__ out) {
    int g = blockIdx.x;
    int t = threadIdx.x;
    float acc = 0.f;
    for (int j = t; j < D1C; j += 256) {
        float v = z[g * D1C + j] * scale[j] + shift[j];
        acc += v * Wl[j];
    }
#pragma unroll
    for (int off = 32; off > 0; off >>= 1) acc += __shfl_xor(acc, off);
    __shared__ float red[4];
    int lane = t & 63, w = t >> 6;
    if (lane == 0) red[w] = acc;
    __syncthreads();
    if (t == 0) out[g] = red[0] + red[1] + red[2] + red[3] + bl[0];
}

extern "C" void kernel_launch(void* const* d_in, const int* in_sizes, int n_in,
                              void* d_out, int out_size, void* d_ws, size_t ws_size,
                              hipStream_t stream) {
    const float* x       = (const float*)d_in[0];
    const int*   ei      = (const int*)d_in[1];
    const int*   batch   = (const int*)d_in[2];
    const float* fpts    = (const float*)d_in[3];
    const float* Wg      = (const float*)d_in[4];
    const float* att_src = (const float*)d_in[5];
    const float* att_dst = (const float*)d_in[6];
    const float* gat_b   = (const float*)d_in[7];
    const float* Wlg     = (const float*)d_in[8];
    const float* blg     = (const float*)d_in[9];
    const float* W1      = (const float*)d_in[10];
    const float* b1      = (const float*)d_in[11];
    const float* g1      = (const float*)d_in[12];
    const float* be1     = (const float*)d_in[13];
    const float* W2      = (const float*)d_in[14];
    const float* b2      = (const float*)d_in[15];
    const float* g2      = (const float*)d_in[16];
    const float* be2     = (const float*)d_in[17];
    const float* W3      = (const float*)d_in[18];
    const float* b3      = (const float*)d_in[19];
    const float* Wf      = (const float*)d_in[20];
    const float* bf      = (const float*)d_in[21];
    const float* gf      = (const float*)d_in[22];
    const float* bef     = (const float*)d_in[23];
    const float* Wl      = (const float*)d_in[24];
    const float* bl      = (const float*)d_in[25];
    float* out = (float*)d_out;

    size_t o = 0;
    auto alloc = [&](size_t nfloats) {
        float* p = (float*)((char*)d_ws + o);
        o += ((nfloats * sizeof(float) + 255) / 256) * 256;
        return p;
    };
    float* xl     = alloc(NN * 64);      // also reused as h1
    float* aggr   = alloc(NN * 64);      // also reused as h2 / z
    float* a_src  = alloc(NN);
    float* a_dst  = alloc(NN);
    float* denom  = alloc(NN);
    float* gsum   = alloc(NG * 64);
    float* gcntf  = alloc(NG);
    float* pooled = alloc(NG * 64);
    float* cbuf   = alloc(NG * (GOUTC + MOUTC));  // [1000,512] concat buffer
    float* scale  = alloc(1024);
    float* shift  = alloc(1024);
    int* gcnt = (int*)gcntf;

    // aliases (xl/aggr dead after graph phase)
    float* h1 = xl;                       // needs 1,024,000 floats (<3.2M)
    float* h2 = aggr;                     // needs 512,000
    float* zb = aggr + 1048576;           // needs 512,000 (no overlap with h2)

    // ---- GAT ----
    k_xl<<<NN / 4, 256, 0, stream>>>(x, Wg, att_src, att_dst, xl, a_src, a_dst);
    k_self_init<<<NN / 4, 256, 0, stream>>>(xl, a_src, a_dst, denom, aggr);
    k_edges<<<NE / 4, 256, 0, stream>>>(ei, xl, a_src, a_dst, denom, aggr);
    hipMemsetAsync(gsum, 0, NG * 64 * sizeof(float), stream);
    hipMemsetAsync(gcnt, 0, NG * sizeof(int), stream);
    k_pool<<<NN / 4, 256, 0, stream>>>(aggr, denom, gat_b, batch, gsum, gcnt);
    k_pooled<<<(NG * 64 + 255) / 256, 256, 0, stream>>>(gsum, gcnt, pooled);
    // gnn_out -> cbuf[:, 0:256]
    k_gemm<false><<<dim3(GOUTC / 64, (NG + 63) / 64), 256, 0, stream>>>(
        pooled, Wlg, blg, cbuf, NG, GOUTC, 64, 512);

    // ---- MLP ----
    k_gemm<false><<<dim3(H1C / 64, (NG + 63) / 64), 256, 0, stream>>>(
        fpts, W1, b1, h1, NG, H1C, FPC, H1C);
    k_bnstats<<<(H1C + 255) / 256, 256, 0, stream>>>(h1, g1, be1, scale, shift, H1C);
    k_bnrelu<<<(NG * H1C + 255) / 256, 256, 0, stream>>>(h1, scale, shift, H1C - 1, NG * H1C);

    k_gemm<false><<<dim3(H2C / 64, (NG + 63) / 64), 256, 0, stream>>>(
        h1, W2, b2, h2, NG, H2C, H1C, H2C);
    k_bnstats<<<(H2C + 255) / 256, 256, 0, stream>>>(h2, g2, be2, scale, shift, H2C);
    k_bnrelu<<<(NG * H2C + 255) / 256, 256, 0, stream>>>(h2, scale, shift, H2C - 1, NG * H2C);

    // mlp_out -> cbuf[:, 256:512]
    k_gemm<false><<<dim3(MOUTC / 64, (NG + 63) / 64), 256, 0, stream>>>(
        h2, W3, b3, cbuf + 256, NG, MOUTC, H2C, 512);

    // ---- fusion head ----
    k_gemm<true><<<dim3(D1C / 64, (NG + 63) / 64), 256, 0, stream>>>(
        cbuf, Wf, bf, zb, NG, D1C, GOUTC + MOUTC, D1C);
    k_bnstats<<<(D1C + 255) / 256, 256, 0, stream>>>(zb, gf, bef, scale, shift, D1C);
    k_final<<<NG, 256, 0, stream>>>(zb, scale, shift, Wl, bl, out);
}

// Round 5
// 568.935 us; speedup vs baseline: 1.9334x; 1.9334x over previous
//
#include <hip/hip_runtime.h>

#define NN 50000
#define NE 800000
#define NG 1000
#define DIN 64
#define HIDC 64
#define GOUTC 256
#define FPC 2048
#define H1C 1024
#define H2C 512
#define MOUTC 256
#define D1C 512
#define EPSV 1e-5f
#define SLOPEV 0.2f

typedef __attribute__((ext_vector_type(8))) short s8v;
typedef __attribute__((ext_vector_type(4))) float f4v;
typedef unsigned short ushort_t;

__device__ inline ushort_t f2b(float f) {
    unsigned u = __builtin_bit_cast(unsigned, f);
    unsigned r = (u + 0x7FFFu + ((u >> 16) & 1u)) >> 16;
    return (ushort_t)r;
}

// ---- GAT: xl = x @ Wg^T ; a_src = xl.att_src ; a_dst = xl.att_dst ----
__global__ void k_xl(const float* __restrict__ x, const float* __restrict__ Wg,
                     const float* __restrict__ att_src, const float* __restrict__ att_dst,
                     float* __restrict__ xl, float* __restrict__ a_src, float* __restrict__ a_dst) {
    __shared__ float Wgs[64][65];
    __shared__ float xs[4][64];
    int t = threadIdx.x;
    int lane = t & 63;
    int w = t >> 6;
    for (int i = t; i < 64 * 64; i += 256) Wgs[i >> 6][i & 63] = Wg[i];
    int node = blockIdx.x * 4 + w;
    xs[w][lane] = x[node * 64 + lane];
    __syncthreads();
    float acc = 0.f;
#pragma unroll
    for (int d = 0; d < 64; ++d) acc += xs[w][d] * Wgs[lane][d];
    xl[node * 64 + lane] = acc;
    float vs = acc * att_src[lane];
    float vd = acc * att_dst[lane];
#pragma unroll
    for (int off = 32; off > 0; off >>= 1) {
        vs += __shfl_xor(vs, off);
        vd += __shfl_xor(vd, off);
    }
    if (lane == 0) { a_src[node] = vs; a_dst[node] = vd; }
}

// ---- self-loop init of denom/aggr (softmax without max-shift; |e| small) ----
__global__ void k_self_init(const float* __restrict__ xl, const float* __restrict__ a_src,
                            const float* __restrict__ a_dst,
                            float* __restrict__ denom, float* __restrict__ aggr) {
    int t = threadIdx.x, lane = t & 63, w = t >> 6;
    int node = blockIdx.x * 4 + w;
    float e = a_src[node] + a_dst[node];
    e = e > 0.f ? e : SLOPEV * e;
    float ex = expf(e);
    if (lane == 0) denom[node] = ex;
    aggr[node * 64 + lane] = ex * xl[node * 64 + lane];
}

// ---- edge pass: atomic accumulate exp(e) and exp(e)*xl[src] into dst ----
__global__ void k_edges(const int* __restrict__ ei, const float* __restrict__ xl,
                        const float* __restrict__ a_src, const float* __restrict__ a_dst,
                        float* __restrict__ denom, float* __restrict__ aggr) {
    int t = threadIdx.x, lane = t & 63, w = t >> 6;
    int e = blockIdx.x * 4 + w;
    if (e >= NE) return;
    int s = ei[e];
    int d = ei[NE + e];
    float ev = a_src[s] + a_dst[d];
    ev = ev > 0.f ? ev : SLOPEV * ev;
    float ex = expf(ev);
    if (lane == 0) atomicAdd(&denom[d], ex);
    atomicAdd(&aggr[d * 64 + lane], ex * xl[s * 64 + lane]);
}

// ---- relu(gat_out) + global mean pool (sums + counts) ----
__global__ void k_pool(const float* __restrict__ aggr, const float* __restrict__ denom,
                       const float* __restrict__ gat_bias, const int* __restrict__ batch,
                       float* __restrict__ gsum, int* __restrict__ gcnt) {
    int t = threadIdx.x, lane = t & 63, w = t >> 6;
    int node = blockIdx.x * 4 + w;
    float v = aggr[node * 64 + lane] / denom[node] + gat_bias[lane];
    v = v > 0.f ? v : 0.f;
    int b = batch[node];
    atomicAdd(&gsum[b * 64 + lane], v);
    if (lane == 0) atomicAdd(&gcnt[b], 1);
}

__global__ void k_pooled(const float* __restrict__ gsum, const int* __restrict__ gcnt,
                         ushort_t* __restrict__ pooled_bf) {
    int i = blockIdx.x * 256 + threadIdx.x;
    if (i < NG * 64) {
        float c = (float)gcnt[i >> 6];
        pooled_bf[i] = f2b(gsum[i] / fmaxf(c, 1.f));
    }
}

// ---- fp32 -> bf16 conversion (8 elems/thread) ----
__global__ void k_f2b(const float* __restrict__ s, ushort_t* __restrict__ d, int n) {
    int i = (blockIdx.x * 256 + threadIdx.x) * 8;
    if (i + 8 <= n) {
#pragma unroll
        for (int j = 0; j < 8; ++j) d[i + j] = f2b(s[i + j]);
    } else {
        for (int j = i; j < n; ++j) d[j] = f2b(s[j]);
    }
}

// ---- bf16 MFMA GEMM: C[M,N](ldc) = A[M,K]bf16 @ B[N,K]bf16^T + bias ----
template <bool RELU, bool OBF16>
__global__ __launch_bounds__(256) void k_mgemm(const ushort_t* __restrict__ A,
                                               const ushort_t* __restrict__ B,
                                               const float* __restrict__ bias, void* Cv,
                                               int M, int N, int K, int ldc) {
    __shared__ ushort_t As[64][40];
    __shared__ ushort_t Bs[64][40];
    int t = threadIdx.x;
    int lane = t & 63, w = t >> 6;
    int wr = w >> 1, wc = w & 1;
    int bm = blockIdx.y * 64, bn = blockIdx.x * 64;
    f4v acc[2][2];
#pragma unroll
    for (int m = 0; m < 2; ++m)
#pragma unroll
        for (int n = 0; n < 2; ++n) acc[m][n] = (f4v){0.f, 0.f, 0.f, 0.f};

    int lr = t >> 2;            // 0..63 : tile row this thread stages
    int lk = (t & 3) * 8;       // 0,8,16,24 : k-offset (halves)
    int arow = bm + lr;
    bool aval = arow < M;
    const ushort_t* aptr = A + (size_t)(aval ? arow : (M - 1)) * K + lk;
    const ushort_t* bptr = B + (size_t)(bn + lr) * K + lk;
    int fr = lane & 15, kg = lane >> 4;

    for (int k0 = 0; k0 < K; k0 += 32) {
        s8v av = {};
        if (aval) av = *(const s8v*)(aptr + k0);
        s8v bv = *(const s8v*)(bptr + k0);
        *(s8v*)&As[lr][lk] = av;
        *(s8v*)&Bs[lr][lk] = bv;
        __syncthreads();
        s8v bfrag0 = *(const s8v*)&Bs[wc * 32 + 0 * 16 + fr][kg * 8];
        s8v bfrag1 = *(const s8v*)&Bs[wc * 32 + 1 * 16 + fr][kg * 8];
#pragma unroll
        for (int m = 0; m < 2; ++m) {
            s8v af = *(const s8v*)&As[wr * 32 + m * 16 + fr][kg * 8];
            acc[m][0] = __builtin_amdgcn_mfma_f32_16x16x32_bf16(af, bfrag0, acc[m][0], 0, 0, 0);
            acc[m][1] = __builtin_amdgcn_mfma_f32_16x16x32_bf16(af, bfrag1, acc[m][1], 0, 0, 0);
        }
        __syncthreads();
    }
    int fq = lane >> 4;
#pragma unroll
    for (int m = 0; m < 2; ++m) {
        int row = bm + wr * 32 + m * 16 + fq * 4;
#pragma unroll
        for (int n = 0; n < 2; ++n) {
            int col = bn + wc * 32 + n * 16 + fr;
            float bb = bias[col];
#pragma unroll
            for (int r = 0; r < 4; ++r) {
                int gr = row + r;
                if (gr < M) {
                    float v = acc[m][n][r] + bb;
                    if (RELU) v = fmaxf(v, 0.f);
                    if (OBF16) ((ushort_t*)Cv)[(size_t)gr * ldc + col] = f2b(v);
                    else ((float*)Cv)[(size_t)gr * ldc + col] = v;
                }
            }
        }
    }
}

// ---- BN: row-split partial sums -> finalize -> normalize(+relu)+bf16 ----
__global__ void k_bnpart(const float* __restrict__ h, float* __restrict__ sum,
                         float* __restrict__ sumsq, int ncols) {
    int col = blockIdx.x * 256 + threadIdx.x;
    int r0 = blockIdx.y * 125;
    float s = 0.f, q = 0.f;
    for (int r = r0; r < r0 + 125; ++r) {
        float v = h[(size_t)r * ncols + col];
        s += v;
        q += v * v;
    }
    atomicAdd(&sum[col], s);
    atomicAdd(&sumsq[col], q);
}

__global__ void k_bnfin(const float* __restrict__ sum, const float* __restrict__ sumsq,
                        const float* __restrict__ gamma, const float* __restrict__ beta,
                        float* __restrict__ scale, float* __restrict__ shift, int ncols) {
    int col = blockIdx.x * 256 + threadIdx.x;
    if (col >= ncols) return;
    float mu = sum[col] * (1.f / NG);
    float var = sumsq[col] * (1.f / NG) - mu * mu;
    float rstd = rsqrtf(var + EPSV);
    float sc = gamma[col] * rstd;
    scale[col] = sc;
    shift[col] = beta[col] - mu * sc;
}

__global__ void k_bnrelu_bf(const float* __restrict__ h, const float* __restrict__ scale,
                            const float* __restrict__ shift, ushort_t* __restrict__ dst,
                            int colmask, int total) {
    int i = (blockIdx.x * 256 + threadIdx.x) * 4;
    if (i < total) {
#pragma unroll
        for (int j = 0; j < 4; ++j) {
            int col = (i + j) & colmask;
            float v = h[i + j] * scale[col] + shift[col];
            dst[i + j] = f2b(fmaxf(v, 0.f));
        }
    }
}

// ---- final: out[g] = sum_j (z[g,j]*scale[j]+shift[j]) * Wl[j] + bl ----
__global__ void k_final(const float* __restrict__ z, const float* __restrict__ scale,
                        const float* __restrict__ shift, const float* __restrict__ Wl,
                        const float* __restrict__ bl, float* __restrict__ out) {
    int g = blockIdx.x;
    int t = threadIdx.x;
    float acc = 0.f;
    for (int j = t; j < D1C; j += 256) {
        float v = z[g * D1C + j] * scale[j] + shift[j];
        acc += v * Wl[j];
    }
#pragma unroll
    for (int off = 32; off > 0; off >>= 1) acc += __shfl_xor(acc, off);
    __shared__ float red[4];
    int lane = t & 63, w = t >> 6;
    if (lane == 0) red[w] = acc;
    __syncthreads();
    if (t == 0) out[g] = red[0] + red[1] + red[2] + red[3] + bl[0];
}

extern "C" void kernel_launch(void* const* d_in, const int* in_sizes, int n_in,
                              void* d_out, int out_size, void* d_ws, size_t ws_size,
                              hipStream_t stream) {
    const float* x       = (const float*)d_in[0];
    const int*   ei      = (const int*)d_in[1];
    const int*   batch   = (const int*)d_in[2];
    const float* fpts    = (const float*)d_in[3];
    const float* Wg      = (const float*)d_in[4];
    const float* att_src = (const float*)d_in[5];
    const float* att_dst = (const float*)d_in[6];
    const float* gat_b   = (const float*)d_in[7];
    const float* Wlg     = (const float*)d_in[8];
    const float* blg     = (const float*)d_in[9];
    const float* W1      = (const float*)d_in[10];
    const float* b1      = (const float*)d_in[11];
    const float* g1      = (const float*)d_in[12];
    const float* be1     = (const float*)d_in[13];
    const float* W2      = (const float*)d_in[14];
    const float* b2      = (const float*)d_in[15];
    const float* g2      = (const float*)d_in[16];
    const float* be2     = (const float*)d_in[17];
    const float* W3      = (const float*)d_in[18];
    const float* b3      = (const float*)d_in[19];
    const float* Wf      = (const float*)d_in[20];
    const float* bf      = (const float*)d_in[21];
    const float* gf      = (const float*)d_in[22];
    const float* bef     = (const float*)d_in[23];
    const float* Wl      = (const float*)d_in[24];
    const float* bl      = (const float*)d_in[25];
    float* out = (float*)d_out;

    size_t o = 0;
    auto alloc = [&](size_t nfloats) {
        float* p = (float*)((char*)d_ws + o);
        o += ((nfloats * sizeof(float) + 255) / 256) * 256;
        return p;
    };
    float* xl    = alloc(NN * 64);   // region R1: later h1f/h2f/zb
    float* aggr  = alloc(NN * 64);   // region R2: later bf16 arena
    float* a_src = alloc(NN);
    float* a_dst = alloc(NN);
    float* denom = alloc(NN);
    float* gsum  = alloc(NG * 64);
    float* gcntf = alloc(NG);
    float* bnbuf = alloc(4096);      // sum | sumsq
    float* scale = alloc(1024);
    float* shift = alloc(1024);
    int* gcnt = (int*)gcntf;
    float* bnsum = bnbuf;
    float* bnsq  = bnbuf + 2048;

    // R1 aliases (xl dead after k_edges)
    float* h1f = xl;                 // [1000,1024]
    float* h2f = xl + 1048576;       // [1000,512]
    float* zb  = xl + 1572864;       // [1000,512]

    // R2 bf16 arena (aggr dead after k_pool); offsets in halves
    ushort_t* U = (ushort_t*)aggr;   // capacity NN*64*2 = 6,400,000 halves
    ushort_t* cbuf_bf   = U + 0;        // [1000,512]   (live: gnn gemm .. Wf gemm)
    ushort_t* pooled_bf = U + 524288;   // [1000,64]
    ushort_t* Wlg_bf    = U + 589824;   // [256,64]
    ushort_t* fpts_bf   = U + 655360;   // [1000,2048]  (dead after gemm1)
    ushort_t* W1_bf     = U + 2703360;  // [1024,2048]  (dead after gemm1)
    ushort_t* W2_bf     = U + 4800512;  // [512,1024]
    ushort_t* h1_bf     = U + 5324800;  // [1000,1024]
    ushort_t* h2_bf     = U + 655360;   // [1000,512]   (reuses fpts region)
    ushort_t* W3_bf     = U + 1200128;  // [256,512]
    ushort_t* Wf_bf     = U + 1331200;  // [512,512]

    // ---- GAT ----
    k_xl<<<NN / 4, 256, 0, stream>>>(x, Wg, att_src, att_dst, xl, a_src, a_dst);
    k_self_init<<<NN / 4, 256, 0, stream>>>(xl, a_src, a_dst, denom, aggr);
    k_edges<<<NE / 4, 256, 0, stream>>>(ei, xl, a_src, a_dst, denom, aggr);
    hipMemsetAsync(gsum, 0, NG * 64 * sizeof(float), stream);
    hipMemsetAsync(gcnt, 0, NG * sizeof(int), stream);
    k_pool<<<NN / 4, 256, 0, stream>>>(aggr, denom, gat_b, batch, gsum, gcnt);
    k_pooled<<<(NG * 64 + 255) / 256, 256, 0, stream>>>(gsum, gcnt, pooled_bf);

    // ---- conversions needed for gnn gemm + gemm1 + gemm2 ----
    k_f2b<<<(GOUTC * 64 + 2047) / 2048, 256, 0, stream>>>(Wlg, Wlg_bf, GOUTC * 64);
    k_f2b<<<(NG * FPC + 2047) / 2048, 256, 0, stream>>>(fpts, fpts_bf, NG * FPC);
    k_f2b<<<(H1C * FPC + 2047) / 2048, 256, 0, stream>>>(W1, W1_bf, H1C * FPC);
    k_f2b<<<(H2C * H1C + 2047) / 2048, 256, 0, stream>>>(W2, W2_bf, H2C * H1C);

    // gnn_out -> cbuf[:, 0:256] (bf16)
    k_mgemm<false, true><<<dim3(GOUTC / 64, 16), 256, 0, stream>>>(
        pooled_bf, Wlg_bf, blg, cbuf_bf, NG, GOUTC, 64, 512);

    // ---- MLP layer 1 ----
    k_mgemm<false, false><<<dim3(H1C / 64, 16), 256, 0, stream>>>(
        fpts_bf, W1_bf, b1, h1f, NG, H1C, FPC, H1C);
    hipMemsetAsync(bnbuf, 0, 4096 * sizeof(float), stream);
    k_bnpart<<<dim3(H1C / 256, 8), 256, 0, stream>>>(h1f, bnsum, bnsq, H1C);
    k_bnfin<<<(H1C + 255) / 256, 256, 0, stream>>>(bnsum, bnsq, g1, be1, scale, shift, H1C);
    k_bnrelu_bf<<<(NG * H1C / 4 + 255) / 256, 256, 0, stream>>>(
        h1f, scale, shift, h1_bf, H1C - 1, NG * H1C);

    // conversions for gemm3/gemmF (fpts/W1 region now dead)
    k_f2b<<<(MOUTC * H2C + 2047) / 2048, 256, 0, stream>>>(W3, W3_bf, MOUTC * H2C);
    k_f2b<<<(D1C * 512 + 2047) / 2048, 256, 0, stream>>>(Wf, Wf_bf, D1C * 512);

    // ---- MLP layer 2 ----
    k_mgemm<false, false><<<dim3(H2C / 64, 16), 256, 0, stream>>>(
        h1_bf, W2_bf, b2, h2f, NG, H2C, H1C, H2C);
    hipMemsetAsync(bnbuf, 0, 4096 * sizeof(float), stream);
    k_bnpart<<<dim3(H2C / 256, 8), 256, 0, stream>>>(h2f, bnsum, bnsq, H2C);
    k_bnfin<<<(H2C + 255) / 256, 256, 0, stream>>>(bnsum, bnsq, g2, be2, scale, shift, H2C);
    k_bnrelu_bf<<<(NG * H2C / 4 + 255) / 256, 256, 0, stream>>>(
        h2f, scale, shift, h2_bf, H2C - 1, NG * H2C);

    // mlp_out -> cbuf[:, 256:512] (bf16)
    k_mgemm<false, true><<<dim3(MOUTC / 64, 16), 256, 0, stream>>>(
        h2_bf, W3_bf, b3, cbuf_bf + 256, NG, MOUTC, H2C, 512);

    // ---- fusion head ----
    k_mgemm<true, false><<<dim3(D1C / 64, 16), 256, 0, stream>>>(
        cbuf_bf, Wf_bf, bf, zb, NG, D1C, GOUTC + MOUTC, D1C);
    hipMemsetAsync(bnbuf, 0, 4096 * sizeof(float), stream);
    k_bnpart<<<dim3(D1C / 256, 8), 256, 0, stream>>>(zb, bnsum, bnsq, D1C);
    k_bnfin<<<(D1C + 255) / 256, 256, 0, stream>>>(bnsum, bnsq, gf, bef, scale, shift, D1C);
    k_final<<<NG, 256, 0, stream>>>(zb, scale, shift, Wl, bl, out);
}